// Round 3
// baseline (212.867 us; speedup 1.0000x reference)
//
#include <hip/hip_runtime.h>

// AdaptiveAttention: softmax is shift-invariant along the reduced axis, so
// out = softmax(alpha * QK^T) @ V. Two kernels:
//  1) prepass: K -> fp16 (row+XOR-swizzled granules, for LDS staging),
//     V -> transposed bf16 in FRAGMENT ORDER (each (dt,c) MFMA fragment of a
//     tile is a contiguous 1KB run), into d_ws.
//  2) attention: BQ=64 (2 waves x 32 queries, 2 query-halves each),
//     1024 blocks. K staged via double-buffered global_load_lds (32KB LDS);
//     V read DIRECTLY from ws with coalesced b128 fragment loads (vmem/L2
//     pipe, which was 9%-idle, instead of the saturated LDS pipe). LDS =
//     40KB -> 4 blocks/CU = 4 independent barrier domains (DMA drain of one
//     block hides under three others' compute). Single-pass fp16 QK^T,
//     unnormalized exp2 softmax (logits bounded; /l at the end), bf16 PV
//     (unnormalized p reaches ~2^40, overflows fp16 but not bf16).
// ws: K region 16 MB + V region 16 MB = 32 MB.

#define S_LEN 2048
#define HD    128
#define BQ    64
#define BK    64
#define NW    2
#define NT    (S_LEN / BK)        // 32 k-tiles
#define KTILE_USH 8192            // 16 KB fp16 K per (head,kt)
#define VTILE_USH 8192            // 16 KB bf16 V^T per (head,kt)
#define VBASE_USH (32 * NT * KTILE_USH)   // 16 MB K region first

typedef __bf16    bf16x8 __attribute__((ext_vector_type(8)));
typedef __bf16    bf16x4 __attribute__((ext_vector_type(4)));
typedef _Float16  f16x8  __attribute__((ext_vector_type(8)));
typedef float     f32x4  __attribute__((ext_vector_type(4)));

__device__ __forceinline__ unsigned short f2bf(float x) {
  unsigned u = __builtin_bit_cast(unsigned, x);
  u = (u + 0x7FFFu + ((u >> 16) & 1u)) >> 16;   // RNE
  return (unsigned short)u;
}
__device__ __forceinline__ unsigned short f2h(float x) {
  _Float16 h = (_Float16)x;                      // v_cvt_f16_f32, RNE
  return __builtin_bit_cast(unsigned short, h);
}
__device__ __forceinline__ float fast_exp2(float x) {
#if __has_builtin(__builtin_amdgcn_exp2f)
  return __builtin_amdgcn_exp2f(x);
#else
  return exp2f(x);
#endif
}

// ---------- prepass: convert + transpose into ws ----------
__global__ __launch_bounds__(256) void attn_prepass_kernel(
    const float* __restrict__ kg, const float* __restrict__ vg,
    unsigned short* __restrict__ ws) {
  __shared__ float T[64 * 130];         // V staging, stride 130 (b64-aligned)
  const int blk  = blockIdx.x;          // head*32 + kt
  const int head = blk >> 5;
  const int kt   = blk & 31;
  const int tid  = threadIdx.x;
  const size_t hoff = (size_t)head * S_LEN * HD;
  const float* kp = kg + hoff + (size_t)kt * BK * HD;
  const float* vp = vg + hoff + (size_t)kt * BK * HD;
  unsigned short* wsK = ws + (size_t)blk * KTILE_USH;
  unsigned short* wsV = ws + VBASE_USH + (size_t)blk * VTILE_USH;

  // K (fp16): granule (key, ch) = dims [ch*8, ch*8+8) of row key.
  // slot = (ch&8) | ((ch&7) ^ (key&7))  -> conflict-free b128 LDS reads.
#pragma unroll
  for (int it = 0; it < 4; ++it) {
    int idx = it * 256 + tid;           // 0..1023
    int key = idx >> 4;
    int ch  = idx & 15;
    const float* src = kp + key * HD + ch * 8;
    float4 a = *(const float4*)src;
    float4 b = *(const float4*)(src + 4);
    float xs[8] = {a.x, a.y, a.z, a.w, b.x, b.y, b.z, b.w};
    union { unsigned short s[8]; uint4 v; } hi;
#pragma unroll
    for (int j = 0; j < 8; ++j) hi.s[j] = f2h(xs[j]);
    int slot = (ch & 8) | ((ch & 7) ^ (key & 7));
    *(uint4*)&wsK[key * 128 + slot * 8] = hi.v;
  }

  // V^T via LDS: phase 1 -- coalesced float2 loads, contiguous LDS rows.
#pragma unroll
  for (int it = 0; it < 16; ++it) {
    int idx = it * 256 + tid;           // 0..4095 float2 granules
    int key = idx >> 6;                 // 64 float2 per row
    int c2  = idx & 63;
    float2 a = *(const float2*)(vp + (size_t)key * HD + c2 * 2);
    *(float2*)&T[key * 130 + c2 * 2] = a;
  }
  __syncthreads();

  // phase 2 -- column gather from LDS, write granules in FRAGMENT ORDER:
  // granule (dim, ch) = keys [ch*8, ch*8+8) of column dim, placed at index
  // (dt*2+c)*64 + g*16 + qi  where dim = dt*16+qi, ch = c*4+g.  The
  // attention wave's (dt,c) fragment read is then one contiguous 1KB.
#pragma unroll
  for (int r = 0; r < 4; ++r) {
    int idx = r * 256 + tid;            // 0..1023
    int dim = idx >> 3;                 // 0..127
    int ch  = idx & 7;
    union { unsigned short s[8]; uint4 v; } gg;
#pragma unroll
    for (int j = 0; j < 8; ++j) gg.s[j] = f2bf(T[(ch * 8 + j) * 130 + dim]);
    int gidx = ((dim >> 4) * 2 + (ch >> 2)) * 64 + (ch & 3) * 16 + (dim & 15);
    *(uint4*)&wsV[gidx * 8] = gg.v;
  }
}

// ---------- attention ----------
__device__ __forceinline__ void stage_k(const unsigned short* __restrict__ wt,
                                        unsigned short* dst, int tid, int w) {
  // 8 rounds x 128 lanes x 16B = 16KB. LDS dest is wave-uniform base (w*64
  // granules) + implicit lane*16B -- the m104/m108 requirement.
#pragma unroll
  for (int r = 0; r < 8; ++r) {
    const unsigned int* gp = (const unsigned int*)(wt + (size_t)(r * 128 + tid) * 8);
    unsigned short* lp = dst + (size_t)(r * 128 + w * 64) * 8;
    __builtin_amdgcn_global_load_lds(
        (const __attribute__((address_space(1))) unsigned int*)gp,
        (__attribute__((address_space(3))) unsigned int*)lp, 16, 0, 0);
  }
}

__global__ __launch_bounds__(128, 2) void adaptive_attn_kernel(
    const float* __restrict__ qg, const unsigned short* __restrict__ ws,
    const float* __restrict__ alphap, float* __restrict__ out) {
  __shared__ unsigned short sBuf[2][KTILE_USH];  // 32 KB K double buffer
  __shared__ unsigned short sP[NW][2][1024];     // 8 KB: per wave/half, XOR-swizzled
  // 40 KB total -> 4 blocks/CU on 160KB LDS

  const int b    = blockIdx.x;                   // 1024 blocks
  const int head = (b & 7) * 4 + ((b >> 3) & 3); // XCD L2 locality swizzle
  const int qt   = b >> 5;                       // 0..31

  const int tid  = threadIdx.x;
  const int w    = tid >> 6;                     // 0..1
  const int lane = tid & 63;
  const int g    = lane >> 4;
  const int qi   = lane & 15;

  const float lscale = alphap[0] * 1.44269504088896f;  // alpha * log2(e)

  // Q fragments (B-operand layout) for both query halves, fp16(lscale*Q).
  f16x8 qf[2][4];
#pragma unroll
  for (int h = 0; h < 2; ++h) {
    const int qrow = qt * BQ + w * 32 + h * 16 + qi;
    const float* qp = qg + (size_t)head * S_LEN * HD + (size_t)qrow * HD;
#pragma unroll
    for (int c = 0; c < 4; ++c) {
      float4 a  = *(const float4*)(qp + c * 32 + g * 8);
      float4 bb = *(const float4*)(qp + c * 32 + g * 8 + 4);
      float xs[8] = {a.x, a.y, a.z, a.w, bb.x, bb.y, bb.z, bb.w};
      union { f16x8 v; _Float16 s[8]; } hh;
#pragma unroll
      for (int j = 0; j < 8; ++j) hh.s[j] = (_Float16)(xs[j] * lscale);
      qf[h][c] = hh.v;
    }
  }

  f32x4 o[2][8];
#pragma unroll
  for (int h = 0; h < 2; ++h)
#pragma unroll
    for (int dt = 0; dt < 8; ++dt) o[h][dt] = (f32x4){0.f, 0.f, 0.f, 0.f};
  float lrun[2] = {0.f, 0.f};

  const unsigned short* wsKh = ws + (size_t)head * NT * KTILE_USH;
  const unsigned short* wsVh = ws + VBASE_USH + (size_t)head * NT * VTILE_USH;

  // Prologue: stage K tile 0 into buffer 0.
  stage_k(wsKh, &sBuf[0][0], tid, w);
  __syncthreads();

  for (int kt = 0; kt < NT; ++kt) {
    const unsigned short* sK = &sBuf[kt & 1][0];

    // V fragments: direct coalesced global b128 loads (vmem pipe, not LDS).
    // Issued here, consumed in PV at the bottom -- a full iteration of slack.
    const unsigned short* vb = wsVh + (size_t)kt * VTILE_USH;
    bf16x8 vf[8][2];
#pragma unroll
    for (int dt = 0; dt < 8; ++dt)
#pragma unroll
      for (int c = 0; c < 2; ++c)
        vf[dt][c] = *(const bf16x8*)&vb[((dt * 2 + c) * 64 + lane) * 8];

    // Prefetch next K tile; its vmcnt drain hides behind compute.
    if (kt + 1 < NT)
      stage_k(wsKh + (size_t)(kt + 1) * KTILE_USH, &sBuf[(kt + 1) & 1][0], tid, w);

    // S^T (64 keys x 32 queries): each K fragment read feeds 2 MFMAs
    // (2 query halves). key&7 == qi&7 since key = mt*16+qi.
    f32x4 st[2][4];
    __builtin_amdgcn_s_setprio(1);
#pragma unroll
    for (int mt = 0; mt < 4; ++mt) {
      f32x4 a0 = (f32x4){0.f, 0.f, 0.f, 0.f};
      f32x4 a1 = (f32x4){0.f, 0.f, 0.f, 0.f};
#pragma unroll
      for (int c = 0; c < 4; ++c) {
        int ch   = c * 4 + g;
        int slot = (ch & 8) | ((ch & 7) ^ (qi & 7));
        f16x8 ah = *(const f16x8*)&sK[(mt * 16 + qi) * 128 + slot * 8];
        a0 = __builtin_amdgcn_mfma_f32_16x16x32_f16(ah, qf[0][c], a0, 0, 0, 0);
        a1 = __builtin_amdgcn_mfma_f32_16x16x32_f16(ah, qf[1][c], a1, 0, 0, 0);
      }
      st[0][mt] = a0; st[1][mt] = a1;
    }
    __builtin_amdgcn_s_setprio(0);

    // Unnormalized softmax: p = exp2(st) (bounded logits; /l at the end).
    // P^T -> A-layout via per-wave per-half XOR-swizzled LDS staging:
    // write granule gr = mt*2+(g>>1), sub = g&1, slot = gr ^ (qi&7).
#pragma unroll
    for (int h = 0; h < 2; ++h) {
      unsigned short* sPh = &sP[w][h][0];
#pragma unroll
      for (int mt = 0; mt < 4; ++mt) {
        float p0 = fast_exp2(st[h][mt][0]);
        float p1 = fast_exp2(st[h][mt][1]);
        float p2 = fast_exp2(st[h][mt][2]);
        float p3 = fast_exp2(st[h][mt][3]);
        lrun[h] += (p0 + p1) + (p2 + p3);
        bf16x4 pv4;
        pv4[0] = (__bf16)p0; pv4[1] = (__bf16)p1;
        pv4[2] = (__bf16)p2; pv4[3] = (__bf16)p3;
        int slot = (mt * 2 + (g >> 1)) ^ (qi & 7);
        *(bf16x4*)&sPh[qi * 64 + slot * 8 + (g & 1) * 4] = pv4;
      }
    }

    bf16x8 pf[2][2];
#pragma unroll
    for (int h = 0; h < 2; ++h)
#pragma unroll
      for (int c = 0; c < 2; ++c) {
        int slot = (c * 4 + g) ^ (qi & 7);   // read granule = c*4+g (8 keys)
        pf[h][c] = *(const bf16x8*)&sP[w][h][qi * 64 + slot * 8];
      }

    // PV from register V fragments: each vf feeds 2 MFMAs (both halves).
    __builtin_amdgcn_s_setprio(1);
#pragma unroll
    for (int dt = 0; dt < 8; ++dt) {
      f32x4 a0 = o[0][dt];
      f32x4 a1 = o[1][dt];
#pragma unroll
      for (int c = 0; c < 2; ++c) {
        a0 = __builtin_amdgcn_mfma_f32_16x16x32_bf16(pf[0][c], vf[dt][c], a0, 0, 0, 0);
        a1 = __builtin_amdgcn_mfma_f32_16x16x32_bf16(pf[1][c], vf[dt][c], a1, 0, 0, 0);
      }
      o[0][dt] = a0; o[1][dt] = a1;
    }
    __builtin_amdgcn_s_setprio(0);

    // One barrier per iteration: (a) all reads of sBuf[kt&1] done before
    // iteration kt+1 prefetches kt+2 into it; (b) drains the kt+1 DMA.
    __syncthreads();
  }

  // Epilogue: reduce l across quads, divide, store fp32.
  float* oph = out + (size_t)head * S_LEN * HD + (size_t)(qt * BQ + w * 32) * HD;
#pragma unroll
  for (int h = 0; h < 2; ++h) {
    float ltot = lrun[h];
    ltot += __shfl_xor(ltot, 16, 64);
    ltot += __shfl_xor(ltot, 32, 64);  // lanes with same qi hold l(query qi)
    float inv[4];
#pragma unroll
    for (int r = 0; r < 4; ++r) {
      float lr = __shfl(ltot, g * 4 + r, 64);
      inv[r] = 1.0f / lr;
    }
    float* op = oph + (size_t)(h * 16) * HD;
#pragma unroll
    for (int dt = 0; dt < 8; ++dt) {
#pragma unroll
      for (int r = 0; r < 4; ++r) {
        op[(size_t)(g * 4 + r) * HD + dt * 16 + qi] = o[h][dt][r] * inv[r];
      }
    }
  }
}

extern "C" void kernel_launch(void* const* d_in, const int* in_sizes, int n_in,
                              void* d_out, int out_size, void* d_ws, size_t ws_size,
                              hipStream_t stream) {
  const float* q     = (const float*)d_in[0];
  const float* k     = (const float*)d_in[1];
  const float* v     = (const float*)d_in[2];
  const float* alpha = (const float*)d_in[3];
  float* out = (float*)d_out;
  unsigned short* ws = (unsigned short*)d_ws;   // needs 32 MB

  hipLaunchKernelGGL(attn_prepass_kernel, dim3(1024), dim3(256), 0, stream,
                     k, v, ws);
  hipLaunchKernelGGL(adaptive_attn_kernel, dim3(1024), dim3(128), 0, stream,
                     q, ws, alpha, out);
}